// Round 12
// baseline (775.336 us; speedup 1.0000x reference)
//
#include <hip/hip_runtime.h>
#include <math.h>

// GraphMatcher R12: k_post = 32 rows/block x ALL columns (grid 128, 1024 thr
// / 16 waves). Each wave computes BOTH 16-row groups per weight stream ->
// weight L2 traffic halved vs R10 with all stage dependencies intra-block
// (fixes R11's broken col-split). SN=1 passes everywhere (stage2: 2 passes,
// stage4: 3 passes Q/K/V); per-wave-private gld16 rings (D=2, NBUF=3), zero
// inner barriers, counted vmcnt, slab rotation. k_attn unchanged (R5+).

typedef unsigned short u16;
typedef unsigned int u32;
typedef __attribute__((ext_vector_type(4))) unsigned int u32x4;
typedef __attribute__((ext_vector_type(2))) unsigned int u32x2;
typedef __attribute__((ext_vector_type(8))) short short8v;
typedef __attribute__((ext_vector_type(4))) float f32x4;

union AB { u32x4 q; u32x2 d[2]; short8v s; };

__device__ __forceinline__ u16 f2bf(float f) {
  u32 u = __builtin_bit_cast(u32, f);
  u32 r = u + 0x7fffu + ((u >> 16) & 1u);
  return (u16)(r >> 16);
}

typedef const __attribute__((address_space(1))) void gas_t;
typedef __attribute__((address_space(3))) void las_t;
__device__ __forceinline__ void gld16(const void* g, void* l) {
  __builtin_amdgcn_global_load_lds((gas_t*)g, (las_t*)l, 16, 0, 0);
}
template<int NN>
__device__ __forceinline__ void waitvm() {
  if constexpr (NN == 0) asm volatile("s_waitcnt vmcnt(0)" ::: "memory");
  else asm volatile("s_waitcnt vmcnt(1)" ::: "memory");
}

// ---- M=16 GEMM, A+B direct from global (k_qkv0 only) ----------------------
template<int SN, int NK>
__device__ __forceinline__ void mm16g(const u16* __restrict__ Ar,
                                      const u16* const (&Br)[SN], f32x4 (&acc)[SN]) {
#pragma unroll
  for (int s = 0; s < SN; ++s) acc[s] = (f32x4){0.f, 0.f, 0.f, 0.f};
  AB a[2], b[2][SN];
  a[0].q = *(const u32x4*)(Ar);
#pragma unroll
  for (int s = 0; s < SN; ++s) b[0][s].q = *(const u32x4*)(Br[s]);
#pragma unroll
  for (int kp = 0; kp < NK; ++kp) {
    const int cu = kp & 1, nx = cu ^ 1;
    if (kp + 1 < NK) {
      a[nx].q = *(const u32x4*)(Ar + (kp + 1) * 32);
#pragma unroll
      for (int s = 0; s < SN; ++s) b[nx][s].q = *(const u32x4*)(Br[s] + (kp + 1) * 32);
    }
#pragma unroll
    for (int s = 0; s < SN; ++s)
      acc[s] = __builtin_amdgcn_mfma_f32_16x16x32_bf16(a[cu].s, b[cu][s].s, acc[s], 0, 0, 0);
  }
}

// ---- k_post pass core: C[32][16 cols] = A_lds[32][K] * Wcol^T -------------
// Wave-private ring (3 x 1KB), zero barriers, counted vmcnt, D=2 prefetch.
// Wcol pre-offset to the wave's 16-column base. Both 16-row A groups per
// slab (weight reuse x2). Swizzled global SOURCE + matching read XOR.
template<int LDB, int NS>
__device__ __forceinline__ void mmw(const u16* __restrict__ Wcol, char* __restrict__ ldsw,
                                    const char* __restrict__ Alds, f32x4 (&acc)[2],
                                    int lane, int l4, int l15, int R) {
  const int xj = (lane & 3) ^ ((lane >> 2) & 3) ^ ((lane >> 4) & 3);
  const int swzr = ((l15 & 3) ^ ((l15 >> 2) & 3)) << 4;
  const u16* gs = Wcol + (size_t)(lane >> 2) * LDB + xj * 8;
  acc[0] = (f32x4){0.f, 0.f, 0.f, 0.f};
  acc[1] = (f32x4){0.f, 0.f, 0.f, 0.f};
#pragma unroll
  for (int d = 0; d < 2; ++d) {
    const int sl = (R + d) & (NS - 1);
    gld16(gs + (size_t)sl * 32, ldsw + d * 1024);
  }
#pragma unroll
  for (int i = 0; i < NS; ++i) {
    if (i < NS - 1) waitvm<1>();
    else waitvm<0>();
    const int s = (i + R) & (NS - 1);
    const char* rb = ldsw + (i % 3) * 1024;
    AB af0, af1, bf;
    af0.q = *(const u32x4*)(Alds + ((l15 * 1024 + s * 64 + l4 * 16) ^ ((l15 & 7) << 4)));
    af1.q = *(const u32x4*)(Alds + (((16 + l15) * 1024 + s * 64 + l4 * 16) ^ ((l15 & 7) << 4)));
    bf.q = *(const u32x4*)(rb + l15 * 64 + ((l4 << 4) ^ swzr));
    acc[0] = __builtin_amdgcn_mfma_f32_16x16x32_bf16(af0.s, bf.s, acc[0], 0, 0, 0);
    acc[1] = __builtin_amdgcn_mfma_f32_16x16x32_bf16(af1.s, bf.s, acc[1], 0, 0, 0);
    if (i + 2 < NS) {
      const int sl = (i + 2 + R) & (NS - 1);
      gld16(gs + (size_t)sl * 32, ldsw + ((i + 2) % 3) * 1024);
    }
  }
}

// ---------------- setup: weight cast/permute + BN fold ----------------------
__global__ void k_setup(const float* __restrict__ Wq, const float* __restrict__ Wk,
                        const float* __restrict__ Wv, const float* __restrict__ Wm,
                        const float* __restrict__ W1, const float* __restrict__ W2,
                        const float* __restrict__ g, const float* __restrict__ be,
                        const float* __restrict__ mu, const float* __restrict__ va,
                        const float* __restrict__ b1, u16* __restrict__ wbf,
                        float* __restrict__ sc, float* __restrict__ sh) {
  int bid = blockIdx.x, tid = threadIdx.x;
  if (bid < 4608) {
    int which = bid / 1152, lb = bid - which * 1152;
    size_t i4 = ((size_t)lb * 256 + tid) * 4;
    int layer = (int)(i4 >> 16), rem = (int)(i4 & 65535);
    int row = rem >> 8, kk = rem & 255;
    const float* src = which == 0 ? Wq : which == 1 ? Wk : which == 2 ? Wv : Wm;
    f32x4 a = *(const f32x4*)(src + i4);
    u16* dl = wbf + (size_t)layer * 655360 + which * 65536;
    if (which < 3) {
      float s = (which == 0) ? 0.125f : 1.0f;
      int rp = ((row & 3) << 6) | (row >> 2);
      u32x2 pk;
      pk[0] = (u32)f2bf(a[0] * s) | ((u32)f2bf(a[1] * s) << 16);
      pk[1] = (u32)f2bf(a[2] * s) | ((u32)f2bf(a[3] * s) << 16);
      *(u32x2*)(dl + rp * 256 + kk) = pk;
    } else {
#pragma unroll
      for (int e = 0; e < 4; ++e) {
        int ci = kk + e, cp = ((ci & 3) << 6) | (ci >> 2);
        dl[row * 256 + cp] = f2bf(a[e]);
      }
    }
  } else if (bid < 9216) {
    int lb = bid - 4608;
    size_t i4 = ((size_t)lb * 256 + tid) * 4;
    int layer = (int)(i4 >> 18);
    size_t rem = i4 & 262143;
    f32x4 a = *(const f32x4*)(W1 + i4);
    u32x2 pk;
    pk[0] = (u32)f2bf(a[0]) | ((u32)f2bf(a[1]) << 16);
    pk[1] = (u32)f2bf(a[2]) | ((u32)f2bf(a[3]) << 16);
    *(u32x2*)(wbf + (size_t)layer * 655360 + 262144 + rem) = pk;
  } else if (bid < 11520) {
    int lb = bid - 9216;
    size_t i4 = ((size_t)lb * 256 + tid) * 4;
    int layer = (int)(i4 >> 17);
    size_t rem = i4 & 131071;
    f32x4 a = *(const f32x4*)(W2 + i4);
    u32x2 pk;
    pk[0] = (u32)f2bf(a[0]) | ((u32)f2bf(a[1]) << 16);
    pk[1] = (u32)f2bf(a[2]) | ((u32)f2bf(a[3]) << 16);
    *(u32x2*)(wbf + (size_t)layer * 655360 + 524288 + rem) = pk;
  } else {
    int i = (bid - 11520) * 256 + tid;
    if (i < 9216) {
      float s = g[i] * rsqrtf(va[i] + 1e-5f);
      sc[i] = s;
      sh[i] = s * (b1[i] - mu[i]) + be[i];
    }
  }
}

// ---------------- init ------------------------------------------------------
__global__ __launch_bounds__(256) void k_init(const float* __restrict__ d0,
                                              const float* __restrict__ d1,
                                              float* __restrict__ dstate,
                                              u16* __restrict__ y) {
  __shared__ float T[64 * 65];
  int b = blockIdx.z, cb = blockIdx.y * 64, nb = blockIdx.x * 64;
  int t = threadIdx.x, th = t >> 4, tl = t & 15;
  const float* src = (b < 2 ? d0 : d1) + (size_t)(b & 1) * 262144;
#pragma unroll
  for (int it = 0; it < 4; ++it) {
    int cl = it * 16 + th;
    f32x4 v = *(const f32x4*)(src + (size_t)(cb + cl) * 1024 + nb + tl * 4);
#pragma unroll
    for (int e = 0; e < 4; ++e) T[cl * 65 + tl * 4 + e] = v[e];
  }
  __syncthreads();
#pragma unroll
  for (int it = 0; it < 4; ++it) {
    int nl = it * 16 + th;
    f32x4 o;
#pragma unroll
    for (int e = 0; e < 4; ++e) o[e] = T[(tl * 4 + e) * 65 + nl];
    *(f32x4*)(dstate + (size_t)b * 262144 + (size_t)(nb + nl) * 256 + cb + tl * 4) = o;
    u32x2 pk;
    pk[0] = (u32)f2bf(o[0]) | ((u32)f2bf(o[1]) << 16);
    pk[1] = (u32)f2bf(o[2]) | ((u32)f2bf(o[3]) << 16);
    *(u32x2*)(y + (size_t)b * 524288 + (size_t)(nb + nl) * 512 + cb + tl * 4) = pk;
  }
}

// ---------------- layer-0 QKV ----------------------------------------------
__global__ __launch_bounds__(512) void k_qkv0(const u16* __restrict__ y,
                                              const u16* __restrict__ wln,
                                              const float* __restrict__ bqn,
                                              const float* __restrict__ bkn,
                                              const float* __restrict__ bvn,
                                              u16* __restrict__ qb, u16* __restrict__ kb,
                                              u16* __restrict__ vb) {
  const int row0 = blockIdx.x * 16, b = row0 >> 10, nb0 = row0 & 1023;
  const int tid = threadIdx.x, w = tid >> 6, lane = tid & 63;
  const int l4 = lane >> 4, l15 = lane & 15;
  const u16* Ar = y + (size_t)(row0 + l15) * 512 + l4 * 8;
  const u16* Br[6];
  f32x4 acc[6];
  int ty[6], cc[6];
#pragma unroll
  for (int s = 0; s < 6; ++s) {
    int gc = w * 96 + s * 16;
    ty[s] = gc >> 8;
    cc[s] = gc & 255;
    Br[s] = wln + ty[s] * 65536 + (size_t)(cc[s] + l15) * 256 + l4 * 8;
  }
  mm16g<6, 8>(Ar, Br, acc);
#pragma unroll
  for (int s = 0; s < 6; ++s) {
    int c = cc[s] + l15;
    int borig = ((c & 63) << 2) | (c >> 6);
    if (ty[s] == 0) {
      float bb = 0.125f * bqn[borig];
#pragma unroll
      for (int r = 0; r < 4; ++r)
        qb[(size_t)b * 262144 + (size_t)(nb0 + l4 * 4 + r) * 256 + c] = f2bf(acc[s][r] + bb);
    } else if (ty[s] == 1) {
      float bb = bkn[borig];
#pragma unroll
      for (int r = 0; r < 4; ++r)
        kb[(size_t)b * 262144 + (size_t)(nb0 + l4 * 4 + r) * 256 + c] = f2bf(acc[s][r] + bb);
    } else {
      float bb = bvn[borig];
      u32x2 pk;
      pk[0] = (u32)f2bf(acc[s][0] + bb) | ((u32)f2bf(acc[s][1] + bb) << 16);
      pk[1] = (u32)f2bf(acc[s][2] + bb) | ((u32)f2bf(acc[s][3] + bb) << 16);
      *(u32x2*)(vb + (size_t)b * 262144 + (size_t)c * 1024 + nb0 + l4 * 4) = pk;
    }
  }
}

// ---------------- flash attention (unchanged, passing since R5) -------------
__global__ __launch_bounds__(512) void k_attn(const u16* __restrict__ qbuf,
                                              const u16* __restrict__ kbuf,
                                              const u16* __restrict__ vbuf,
                                              u16* __restrict__ att, int crossmask) {
  __shared__ char Kt[2][2][8192];
  __shared__ char Vt[2][2][8192];
  __shared__ char Ps[8][2304];
  __shared__ float Ms[4][16], Ls[4][16], Os[4][16][68];
  const int nb = blockIdx.x * 64;
  const int bh = blockIdx.y, b = bh >> 2, h = bh & 3;
  const int srcb = b ^ crossmask;
  const int tid = threadIdx.x, w = tid >> 6, lane = tid & 63;
  const int l4 = lane >> 4, l15 = lane & 15;
  const int qt = w & 3, half = w >> 2;
  char* P = Ps[w];
  const u16* Qb = qbuf + (size_t)b * 262144 + h * 64;
  const u16* Kb = kbuf + (size_t)srcb * 262144 + h * 64;
  const u16* Vb = vbuf + (size_t)srcb * 262144 + (size_t)h * 65536;
  const int srow = tid >> 3, sj = (tid & 7) * 16, sx = sj ^ ((srow & 7) << 4);
  const u16* gK[2] = {Kb, Kb + 512 * 256};
  const u16* gV[2] = {Vb, Vb + 512};

  const int qrow = nb + qt * 16;
  AB qf[2];
#pragma unroll
  for (int ks = 0; ks < 2; ++ks)
    qf[ks].q = *(const u32x4*)(Qb + (size_t)(qrow + l15) * 256 + ks * 32 + l4 * 8);

  u32x4 sk[2], sv[2];
#pragma unroll
  for (int H = 0; H < 2; ++H) {
    sk[H] = *(const u32x4*)((const char*)(gK[H] + (size_t)srow * 256) + sj);
    sv[H] = *(const u32x4*)((const char*)(gV[H] + (size_t)srow * 1024) + sj);
  }
#pragma unroll
  for (int H = 0; H < 2; ++H) {
    *(u32x4*)(Kt[H][0] + srow * 128 + sx) = sk[H];
    *(u32x4*)(Vt[H][0] + srow * 128 + sx) = sv[H];
  }
  __syncthreads();

  f32x4 oacc[4];
#pragma unroll
  for (int s = 0; s < 4; ++s) oacc[s] = (f32x4){0.f, 0.f, 0.f, 0.f};
  float mst = -1e30f, lst = 0.f;

#pragma unroll
  for (int mt = 0; mt < 8; ++mt) {
    const int cur = mt & 1, nx = cur ^ 1;
    if (mt < 7) {
#pragma unroll
      for (int H = 0; H < 2; ++H) {
        sk[H] = *(const u32x4*)((const char*)(gK[H] + (size_t)((mt + 1) * 64 + srow) * 256) + sj);
        sv[H] = *(const u32x4*)((const char*)(gV[H] + (size_t)srow * 1024 + (mt + 1) * 64) + sj);
      }
    }
    f32x4 sa[4];
#pragma unroll
    for (int sm = 0; sm < 4; ++sm) {
      sa[sm] = (f32x4){0.f, 0.f, 0.f, 0.f};
#pragma unroll
      for (int ks = 0; ks < 2; ++ks) {
        AB kf;
        int rr = sm * 16 + l15;
        kf.q = *(const u32x4*)(Kt[half][cur] + rr * 128 + ((ks * 64 + l4 * 16) ^ ((rr & 7) << 4)));
        sa[sm] = __builtin_amdgcn_mfma_f32_16x16x32_bf16(kf.s, qf[ks].s, sa[sm], 0, 0, 0);
      }
    }
    float m1 = fmaxf(fmaxf(fmaxf(sa[0][0], sa[0][1]), fmaxf(sa[0][2], sa[0][3])),
                     fmaxf(fmaxf(sa[1][0], sa[1][1]), fmaxf(sa[1][2], sa[1][3])));
    float m2 = fmaxf(fmaxf(fmaxf(sa[2][0], sa[2][1]), fmaxf(sa[2][2], sa[2][3])),
                     fmaxf(fmaxf(sa[3][0], sa[3][1]), fmaxf(sa[3][2], sa[3][3])));
    m1 = fmaxf(m1, m2);
    m1 = fmaxf(m1, __shfl_xor(m1, 16));
    m1 = fmaxf(m1, __shfl_xor(m1, 32));
    float mnew = fmaxf(mst, m1);
    float corr = __expf(mst - mnew);
    mst = mnew;
    float rs = 0.f;
#pragma unroll
    for (int sm = 0; sm < 4; ++sm)
#pragma unroll
      for (int r = 0; r < 4; ++r) {
        float p = __expf(sa[sm][r] - mnew);
        sa[sm][r] = p;
        rs += p;
      }
    rs += __shfl_xor(rs, 16);
    rs += __shfl_xor(rs, 32);
    lst = lst * corr + rs;
#pragma unroll
    for (int r = 0; r < 4; ++r) {
      float cr = __shfl(corr, l4 * 4 + r);
#pragma unroll
      for (int s = 0; s < 4; ++s) oacc[s][r] *= cr;
    }
#pragma unroll
    for (int sm = 0; sm < 4; ++sm) {
      u32x2 pk;
      pk[0] = (u32)f2bf(sa[sm][0]) | ((u32)f2bf(sa[sm][1]) << 16);
      pk[1] = (u32)f2bf(sa[sm][2]) | ((u32)f2bf(sa[sm][3]) << 16);
      *(u32x2*)(P + l15 * 136 + (sm * 16 + l4 * 4) * 2) = pk;
    }
#pragma unroll
    for (int ks = 0; ks < 2; ++ks) {
      AB pf;
      const char* ra = P + l15 * 136 + ks * 64 + l4 * 16;
      pf.d[0] = *(const u32x2*)ra;
      pf.d[1] = *(const u32x2*)(ra + 8);
#pragma unroll
      for (int s = 0; s < 4; ++s) {
        AB vf;
        int rr = s * 16 + l15;
        vf.q = *(const u32x4*)(Vt[half][cur] + rr * 128 + ((ks * 64 + l4 * 16) ^ ((rr & 7) << 4)));
        oacc[s] = __builtin_amdgcn_mfma_f32_16x16x32_bf16(pf.s, vf.s, oacc[s], 0, 0, 0);
      }
    }
    if (mt < 7) {
#pragma unroll
      for (int H = 0; H < 2; ++H) {
        *(u32x4*)(Kt[H][nx] + srow * 128 + sx) = sk[H];
        *(u32x4*)(Vt[H][nx] + srow * 128 + sx) = sv[H];
      }
    }
    __syncthreads();
  }
  if (half == 1) {
    Ms[qt][l15] = mst;
    Ls[qt][l15] = lst;
#pragma unroll
    for (int s = 0; s < 4; ++s)
#pragma unroll
      for (int r = 0; r < 4; ++r) Os[qt][l4 * 4 + r][s * 16 + l15] = oacc[s][r];
  }
  __syncthreads();
  if (half == 0) {
    float mb = Ms[qt][l15], lb = Ls[qt][l15];
    float M = fmaxf(mst, mb);
    float ea = __expf(mst - M), eb = __expf(mb - M);
    float rl = 1.f / (lst * ea + lb * eb);
    float fa = ea * rl, fb = eb * rl;
#pragma unroll
    for (int r = 0; r < 4; ++r) {
      float far = __shfl(fa, l4 * 4 + r);
      float fbr = __shfl(fb, l4 * 4 + r);
      int n = nb + qt * 16 + l4 * 4 + r;
#pragma unroll
      for (int s = 0; s < 4; ++s) {
        float ov = oacc[s][r] * far + Os[qt][l4 * 4 + r][s * 16 + l15] * fbr;
        att[(size_t)b * 262144 + (size_t)n * 256 + h * 64 + s * 16 + l15] = f2bf(ov);
      }
    }
  }
}

// ---------------- fused post: merge + mlp + residual + next QKV -------------
// grid 128 (32 rows each), 1024 thr / 16 waves. Wave owns 16 cols per pass.
__global__ __launch_bounds__(1024) void k_post(
    const u16* __restrict__ att, const u16* __restrict__ wl, const u16* __restrict__ wln,
    const float* __restrict__ bm, const float* __restrict__ sc, const float* __restrict__ sh,
    const float* __restrict__ b2, const float* __restrict__ bqn,
    const float* __restrict__ bkn, const float* __restrict__ bvn,
    float* __restrict__ dstate, u16* __restrict__ y, u16* __restrict__ qb,
    u16* __restrict__ kb, u16* __restrict__ vb, float* __restrict__ out, int cross, int j,
    int last) {
  __shared__ char yT[32768];   // [32 rows][512ch] bf16, 16B-XOR swizzled
  __shared__ char hT[32768];   // att copy (x-half of rows), then stage2 out
  __shared__ char Wb[49152];   // 16 per-wave rings x 3KB
  const int bid = blockIdx.x;
  const int row0 = bid * 32, b = row0 >> 10, nb0 = row0 & 1023;
  const int tid = threadIdx.x, w = tid >> 6, lane = tid & 63;
  const int l4 = lane >> 4, l15 = lane & 15;
  char* ring = Wb + w * 3072;

  {  // stage yT (32 rows x 512 ch) + att -> hT (32 rows x 256 ch)
#pragma unroll
    for (int it = 0; it < 2; ++it) {
      int idx = it * 1024 + tid;
      int rr = idx >> 6, ch = idx & 63;
      u32x4 v = *(const u32x4*)(y + (size_t)(row0 + rr) * 512 + ch * 8);
      *(u32x4*)(yT + ((rr * 1024 + ch * 16) ^ ((rr & 7) << 4))) = v;
    }
    {
      int ra = tid >> 5, ca = tid & 31;
      u32x4 va = *(const u32x4*)(att + (size_t)(row0 + ra) * 256 + ca * 8);
      *(u32x4*)(hT + ((ra * 1024 + ca * 16) ^ ((ra & 7) << 4))) = va;
    }
  }
  __syncthreads();
  {  // stage1: msg = att @ Wm^T + bm -> yT[.,256+c]
    f32x4 acc[2];
    mmw<256, 8>(wl + 196608 + (size_t)(w * 16) * 256, ring, hT, acc, lane, l4, l15, bid & 7);
    int c = w * 16 + l15;
    float bb = bm[c];
#pragma unroll
    for (int g = 0; g < 2; ++g)
#pragma unroll
      for (int r = 0; r < 4; ++r) {
        int rw = g * 16 + l4 * 4 + r;
        *(u16*)(yT + ((rw * 1024 + (256 + c) * 2) ^ ((rw & 7) << 4))) = f2bf(acc[g][r] + bb);
      }
  }
  __syncthreads();
  {  // stage2: h = relu(sc*(W1 y)+sh) -> hT  (two 256-col passes)
#pragma unroll
    for (int p = 0; p < 2; ++p) {
      f32x4 acc[2];
      const int colbase = p * 256 + w * 16;
      mmw<512, 16>(wl + 262144 + (size_t)colbase * 512, ring, yT, acc, lane, l4, l15,
                   (bid + p * 5) & 15);
      int c = colbase + l15;
      float s_ = sc[c], t_ = sh[c];
#pragma unroll
      for (int g = 0; g < 2; ++g)
#pragma unroll
        for (int r = 0; r < 4; ++r) {
          int rw = g * 16 + l4 * 4 + r;
          *(u16*)(hT + ((rw * 1024 + c * 2) ^ ((rw & 7) << 4))) =
              f2bf(fmaxf(s_ * acc[g][r] + t_, 0.f));
        }
    }
  }
  __syncthreads();
  {  // stage3: delta = W2 h + b2 ; residual ; y ; yT x-half ; out
    f32x4 acc[2];
    mmw<512, 16>(wl + 524288 + (size_t)(w * 16) * 512, ring, hT, acc, lane, l4, l15,
                 bid & 15);
    float* ob = out + (size_t)(((b >> 1) * 9 + j) * 2 + (b & 1)) * 262144;
    int c = w * 16 + l15;
    float bb = b2[c];
#pragma unroll
    for (int g = 0; g < 2; ++g)
#pragma unroll
      for (int r = 0; r < 4; ++r) {
        int rw = g * 16 + l4 * 4 + r;
        size_t di = (size_t)(row0 + rw) * 256 + c;
        float nv = dstate[di] + acc[g][r] + bb;
        dstate[di] = nv;
        u16 bv16 = f2bf(nv);
        y[(size_t)(row0 + rw) * 512 + c] = bv16;
        *(u16*)(yT + ((rw * 1024 + c * 2) ^ ((rw & 7) << 4))) = bv16;
        if (cross) ob[(size_t)c * 1024 + nb0 + rw] = nv;
      }
  }
  if (last) return;
  __syncthreads();
  {  // stage4: next-layer QKV (three 256-col passes: Q, K, V)
#pragma unroll
    for (int p = 0; p < 3; ++p) {
      f32x4 acc[2];
      mmw<256, 8>(wln + p * 65536 + (size_t)(w * 16) * 256, ring, yT, acc, lane, l4, l15,
                  (bid + p * 3) & 7);
      int c = w * 16 + l15;
      int borig = ((c & 63) << 2) | (c >> 6);
      if (p == 0) {
        float bb = 0.125f * bqn[borig];
#pragma unroll
        for (int g = 0; g < 2; ++g)
#pragma unroll
          for (int r = 0; r < 4; ++r)
            qb[(size_t)b * 262144 + (size_t)(nb0 + g * 16 + l4 * 4 + r) * 256 + c] =
                f2bf(acc[g][r] + bb);
      } else if (p == 1) {
        float bb = bkn[borig];
#pragma unroll
        for (int g = 0; g < 2; ++g)
#pragma unroll
          for (int r = 0; r < 4; ++r)
            kb[(size_t)b * 262144 + (size_t)(nb0 + g * 16 + l4 * 4 + r) * 256 + c] =
                f2bf(acc[g][r] + bb);
      } else {
        float bb = bvn[borig];
#pragma unroll
        for (int g = 0; g < 2; ++g) {
          u32x2 pk;
          pk[0] = (u32)f2bf(acc[g][0] + bb) | ((u32)f2bf(acc[g][1] + bb) << 16);
          pk[1] = (u32)f2bf(acc[g][2] + bb) | ((u32)f2bf(acc[g][3] + bb) << 16);
          *(u32x2*)(vb + (size_t)b * 262144 + (size_t)c * 1024 + nb0 + g * 16 + l4 * 4) = pk;
        }
      }
    }
  }
}

// ---------------- host ------------------------------------------------------
extern "C" void kernel_launch(void* const* d_in, const int* in_sizes, int n_in,
                              void* d_out, int out_size, void* d_ws, size_t ws_size,
                              hipStream_t stream) {
  const float* desc0 = (const float*)d_in[0];
  const float* desc1 = (const float*)d_in[1];
  const float* Wq = (const float*)d_in[2];
  const float* bq = (const float*)d_in[3];
  const float* Wk = (const float*)d_in[4];
  const float* bk = (const float*)d_in[5];
  const float* Wv = (const float*)d_in[6];
  const float* bv = (const float*)d_in[7];
  const float* Wm = (const float*)d_in[8];
  const float* bm = (const float*)d_in[9];
  const float* W1 = (const float*)d_in[10];
  const float* b1 = (const float*)d_in[11];
  const float* gamma = (const float*)d_in[12];
  const float* beta = (const float*)d_in[13];
  const float* mu = (const float*)d_in[14];
  const float* var = (const float*)d_in[15];
  const float* W2 = (const float*)d_in[16];
  const float* b2 = (const float*)d_in[17];

  char* ws = (char*)d_ws;
  float* dstate = (float*)ws;                   // 4 MB
  u16* y = (u16*)(ws + ((size_t)4 << 20));      // 4 MB
  u16* qb = (u16*)(ws + ((size_t)8 << 20));     // 2 MB
  u16* kb = (u16*)(ws + ((size_t)10 << 20));    // 2 MB
  u16* vb = (u16*)(ws + ((size_t)12 << 20));    // 2 MB
  u16* attb = (u16*)(ws + ((size_t)14 << 20));  // 2 MB
  u16* wbf = (u16*)(ws + ((size_t)16 << 20));   // 23.6 MB
  float* scb = (float*)(ws + ((size_t)40 << 20));
  float* shb = (float*)(ws + ((size_t)41 << 20));

  k_setup<<<11556, 256, 0, stream>>>(Wq, Wk, Wv, Wm, W1, W2, gamma, beta, mu, var, b1,
                                     wbf, scb, shb);
  k_init<<<dim3(16, 4, 4), 256, 0, stream>>>(desc0, desc1, dstate, y);
  k_qkv0<<<256, 512, 0, stream>>>(y, wbf, bq, bk, bv, qb, kb, vb);

  for (int i = 0; i < 18; ++i) {
    int cross = i & 1;
    const u16* wl = wbf + (size_t)i * 655360;
    int nl = (i < 17) ? i + 1 : 0;
    const u16* wln = wbf + (size_t)nl * 655360;
    k_attn<<<dim3(16, 16), 512, 0, stream>>>(qb, kb, vb, attb, cross ? 2 : 0);
    k_post<<<128, 1024, 0, stream>>>(attb, wl, wln, bm + i * 256, scb + (size_t)i * 512,
                                     shb + (size_t)i * 512, b2 + i * 256, bq + nl * 256,
                                     bk + nl * 256, bv + nl * 256, dstate, y, qb, kb, vb,
                                     (float*)d_out, cross, i >> 1, i == 17);
  }
}

// Round 13
// 692.949 us; speedup vs baseline: 1.1189x; 1.1189x over previous
//
#include <hip/hip_runtime.h>
#include <math.h>

// GraphMatcher R13: R10 geometry (grid 256, 16 rows/block, 1024 thr/16 waves)
// with DEEP per-wave staging rings: D=6 slabs in flight (NBUF=7 x 1KB/wave),
// all passes SN=1 (stage2 = 2 passes, stage4 = 3 passes). Zero inner
// barriers, counted vmcnt, slab rotation. k_attn unchanged (passing R5+).

typedef unsigned short u16;
typedef unsigned int u32;
typedef __attribute__((ext_vector_type(4))) unsigned int u32x4;
typedef __attribute__((ext_vector_type(2))) unsigned int u32x2;
typedef __attribute__((ext_vector_type(8))) short short8v;
typedef __attribute__((ext_vector_type(4))) float f32x4;

union AB { u32x4 q; u32x2 d[2]; short8v s; };

__device__ __forceinline__ u16 f2bf(float f) {
  u32 u = __builtin_bit_cast(u32, f);
  u32 r = u + 0x7fffu + ((u >> 16) & 1u);
  return (u16)(r >> 16);
}

typedef const __attribute__((address_space(1))) void gas_t;
typedef __attribute__((address_space(3))) void las_t;
__device__ __forceinline__ void gld16(const void* g, void* l) {
  __builtin_amdgcn_global_load_lds((gas_t*)g, (las_t*)l, 16, 0, 0);
}
template<int NN>
__device__ __forceinline__ void waitvm() {
  if constexpr (NN == 0) asm volatile("s_waitcnt vmcnt(0)" ::: "memory");
  else if constexpr (NN == 1) asm volatile("s_waitcnt vmcnt(1)" ::: "memory");
  else if constexpr (NN == 2) asm volatile("s_waitcnt vmcnt(2)" ::: "memory");
  else if constexpr (NN == 3) asm volatile("s_waitcnt vmcnt(3)" ::: "memory");
  else if constexpr (NN == 4) asm volatile("s_waitcnt vmcnt(4)" ::: "memory");
  else asm volatile("s_waitcnt vmcnt(5)" ::: "memory");
}

// ---- M=16 GEMM, A+B direct from global (k_qkv0 only) ----------------------
template<int SN, int NK>
__device__ __forceinline__ void mm16g(const u16* __restrict__ Ar,
                                      const u16* const (&Br)[SN], f32x4 (&acc)[SN]) {
#pragma unroll
  for (int s = 0; s < SN; ++s) acc[s] = (f32x4){0.f, 0.f, 0.f, 0.f};
  AB a[2], b[2][SN];
  a[0].q = *(const u32x4*)(Ar);
#pragma unroll
  for (int s = 0; s < SN; ++s) b[0][s].q = *(const u32x4*)(Br[s]);
#pragma unroll
  for (int kp = 0; kp < NK; ++kp) {
    const int cu = kp & 1, nx = cu ^ 1;
    if (kp + 1 < NK) {
      a[nx].q = *(const u32x4*)(Ar + (kp + 1) * 32);
#pragma unroll
      for (int s = 0; s < SN; ++s) b[nx][s].q = *(const u32x4*)(Br[s] + (kp + 1) * 32);
    }
#pragma unroll
    for (int s = 0; s < SN; ++s)
      acc[s] = __builtin_amdgcn_mfma_f32_16x16x32_bf16(a[cu].s, b[cu][s].s, acc[s], 0, 0, 0);
  }
}

// ---- k_post pass core: C[16][16 cols] = A_lds[16][K] * Wcol^T -------------
// Wave-private ring (NBUF x 1KB), zero barriers, counted vmcnt, depth-D.
template<int LDB, int NS, int D>
__device__ __forceinline__ void mmw(const u16* __restrict__ Wcol, char* __restrict__ ldsw,
                                    const char* __restrict__ Alds, f32x4& acc0,
                                    int lane, int l4, int l15, int R) {
  constexpr int DI = D < NS ? D : NS;
  constexpr int NBUF = DI + 1;
  const int xj = (lane & 3) ^ ((lane >> 2) & 3) ^ ((lane >> 4) & 3);
  const int swzr = ((l15 & 3) ^ ((l15 >> 2) & 3)) << 4;
  const u16* gs = Wcol + (size_t)(lane >> 2) * LDB + xj * 8;
  acc0 = (f32x4){0.f, 0.f, 0.f, 0.f};
#pragma unroll
  for (int d = 0; d < DI; ++d) {
    const int sl = (R + d) & (NS - 1);
    gld16(gs + (size_t)sl * 32, ldsw + d * 1024);
  }
#pragma unroll
  for (int i = 0; i < NS; ++i) {
    const int rem = NS - 1 - i;
    if (rem >= DI - 1) waitvm<DI - 1>();
    else if (rem == 4) waitvm<4>();
    else if (rem == 3) waitvm<3>();
    else if (rem == 2) waitvm<2>();
    else if (rem == 1) waitvm<1>();
    else waitvm<0>();
    const int s = (i + R) & (NS - 1);
    const char* rb = ldsw + (i % NBUF) * 1024;
    AB af, bf;
    af.q = *(const u32x4*)(Alds + ((l15 * 1024 + s * 64 + l4 * 16) ^ ((l15 & 7) << 4)));
    bf.q = *(const u32x4*)(rb + l15 * 64 + ((l4 << 4) ^ swzr));
    acc0 = __builtin_amdgcn_mfma_f32_16x16x32_bf16(af.s, bf.s, acc0, 0, 0, 0);
    if (i + DI < NS) {
      const int sl = (i + DI + R) & (NS - 1);
      gld16(gs + (size_t)sl * 32, ldsw + ((i + DI) % NBUF) * 1024);
    }
  }
}

// ---------------- setup: weight cast/permute + BN fold ----------------------
__global__ void k_setup(const float* __restrict__ Wq, const float* __restrict__ Wk,
                        const float* __restrict__ Wv, const float* __restrict__ Wm,
                        const float* __restrict__ W1, const float* __restrict__ W2,
                        const float* __restrict__ g, const float* __restrict__ be,
                        const float* __restrict__ mu, const float* __restrict__ va,
                        const float* __restrict__ b1, u16* __restrict__ wbf,
                        float* __restrict__ sc, float* __restrict__ sh) {
  int bid = blockIdx.x, tid = threadIdx.x;
  if (bid < 4608) {
    int which = bid / 1152, lb = bid - which * 1152;
    size_t i4 = ((size_t)lb * 256 + tid) * 4;
    int layer = (int)(i4 >> 16), rem = (int)(i4 & 65535);
    int row = rem >> 8, kk = rem & 255;
    const float* src = which == 0 ? Wq : which == 1 ? Wk : which == 2 ? Wv : Wm;
    f32x4 a = *(const f32x4*)(src + i4);
    u16* dl = wbf + (size_t)layer * 655360 + which * 65536;
    if (which < 3) {
      float s = (which == 0) ? 0.125f : 1.0f;
      int rp = ((row & 3) << 6) | (row >> 2);
      u32x2 pk;
      pk[0] = (u32)f2bf(a[0] * s) | ((u32)f2bf(a[1] * s) << 16);
      pk[1] = (u32)f2bf(a[2] * s) | ((u32)f2bf(a[3] * s) << 16);
      *(u32x2*)(dl + rp * 256 + kk) = pk;
    } else {
#pragma unroll
      for (int e = 0; e < 4; ++e) {
        int ci = kk + e, cp = ((ci & 3) << 6) | (ci >> 2);
        dl[row * 256 + cp] = f2bf(a[e]);
      }
    }
  } else if (bid < 9216) {
    int lb = bid - 4608;
    size_t i4 = ((size_t)lb * 256 + tid) * 4;
    int layer = (int)(i4 >> 18);
    size_t rem = i4 & 262143;
    f32x4 a = *(const f32x4*)(W1 + i4);
    u32x2 pk;
    pk[0] = (u32)f2bf(a[0]) | ((u32)f2bf(a[1]) << 16);
    pk[1] = (u32)f2bf(a[2]) | ((u32)f2bf(a[3]) << 16);
    *(u32x2*)(wbf + (size_t)layer * 655360 + 262144 + rem) = pk;
  } else if (bid < 11520) {
    int lb = bid - 9216;
    size_t i4 = ((size_t)lb * 256 + tid) * 4;
    int layer = (int)(i4 >> 17);
    size_t rem = i4 & 131071;
    f32x4 a = *(const f32x4*)(W2 + i4);
    u32x2 pk;
    pk[0] = (u32)f2bf(a[0]) | ((u32)f2bf(a[1]) << 16);
    pk[1] = (u32)f2bf(a[2]) | ((u32)f2bf(a[3]) << 16);
    *(u32x2*)(wbf + (size_t)layer * 655360 + 524288 + rem) = pk;
  } else {
    int i = (bid - 11520) * 256 + tid;
    if (i < 9216) {
      float s = g[i] * rsqrtf(va[i] + 1e-5f);
      sc[i] = s;
      sh[i] = s * (b1[i] - mu[i]) + be[i];
    }
  }
}

// ---------------- init ------------------------------------------------------
__global__ __launch_bounds__(256) void k_init(const float* __restrict__ d0,
                                              const float* __restrict__ d1,
                                              float* __restrict__ dstate,
                                              u16* __restrict__ y) {
  __shared__ float T[64 * 65];
  int b = blockIdx.z, cb = blockIdx.y * 64, nb = blockIdx.x * 64;
  int t = threadIdx.x, th = t >> 4, tl = t & 15;
  const float* src = (b < 2 ? d0 : d1) + (size_t)(b & 1) * 262144;
#pragma unroll
  for (int it = 0; it < 4; ++it) {
    int cl = it * 16 + th;
    f32x4 v = *(const f32x4*)(src + (size_t)(cb + cl) * 1024 + nb + tl * 4);
#pragma unroll
    for (int e = 0; e < 4; ++e) T[cl * 65 + tl * 4 + e] = v[e];
  }
  __syncthreads();
#pragma unroll
  for (int it = 0; it < 4; ++it) {
    int nl = it * 16 + th;
    f32x4 o;
#pragma unroll
    for (int e = 0; e < 4; ++e) o[e] = T[(tl * 4 + e) * 65 + nl];
    *(f32x4*)(dstate + (size_t)b * 262144 + (size_t)(nb + nl) * 256 + cb + tl * 4) = o;
    u32x2 pk;
    pk[0] = (u32)f2bf(o[0]) | ((u32)f2bf(o[1]) << 16);
    pk[1] = (u32)f2bf(o[2]) | ((u32)f2bf(o[3]) << 16);
    *(u32x2*)(y + (size_t)b * 524288 + (size_t)(nb + nl) * 512 + cb + tl * 4) = pk;
  }
}

// ---------------- layer-0 QKV ----------------------------------------------
__global__ __launch_bounds__(512) void k_qkv0(const u16* __restrict__ y,
                                              const u16* __restrict__ wln,
                                              const float* __restrict__ bqn,
                                              const float* __restrict__ bkn,
                                              const float* __restrict__ bvn,
                                              u16* __restrict__ qb, u16* __restrict__ kb,
                                              u16* __restrict__ vb) {
  const int row0 = blockIdx.x * 16, b = row0 >> 10, nb0 = row0 & 1023;
  const int tid = threadIdx.x, w = tid >> 6, lane = tid & 63;
  const int l4 = lane >> 4, l15 = lane & 15;
  const u16* Ar = y + (size_t)(row0 + l15) * 512 + l4 * 8;
  const u16* Br[6];
  f32x4 acc[6];
  int ty[6], cc[6];
#pragma unroll
  for (int s = 0; s < 6; ++s) {
    int gc = w * 96 + s * 16;
    ty[s] = gc >> 8;
    cc[s] = gc & 255;
    Br[s] = wln + ty[s] * 65536 + (size_t)(cc[s] + l15) * 256 + l4 * 8;
  }
  mm16g<6, 8>(Ar, Br, acc);
#pragma unroll
  for (int s = 0; s < 6; ++s) {
    int c = cc[s] + l15;
    int borig = ((c & 63) << 2) | (c >> 6);
    if (ty[s] == 0) {
      float bb = 0.125f * bqn[borig];
#pragma unroll
      for (int r = 0; r < 4; ++r)
        qb[(size_t)b * 262144 + (size_t)(nb0 + l4 * 4 + r) * 256 + c] = f2bf(acc[s][r] + bb);
    } else if (ty[s] == 1) {
      float bb = bkn[borig];
#pragma unroll
      for (int r = 0; r < 4; ++r)
        kb[(size_t)b * 262144 + (size_t)(nb0 + l4 * 4 + r) * 256 + c] = f2bf(acc[s][r] + bb);
    } else {
      float bb = bvn[borig];
      u32x2 pk;
      pk[0] = (u32)f2bf(acc[s][0] + bb) | ((u32)f2bf(acc[s][1] + bb) << 16);
      pk[1] = (u32)f2bf(acc[s][2] + bb) | ((u32)f2bf(acc[s][3] + bb) << 16);
      *(u32x2*)(vb + (size_t)b * 262144 + (size_t)c * 1024 + nb0 + l4 * 4) = pk;
    }
  }
}

// ---------------- flash attention (unchanged, passing since R5) -------------
__global__ __launch_bounds__(512) void k_attn(const u16* __restrict__ qbuf,
                                              const u16* __restrict__ kbuf,
                                              const u16* __restrict__ vbuf,
                                              u16* __restrict__ att, int crossmask) {
  __shared__ char Kt[2][2][8192];
  __shared__ char Vt[2][2][8192];
  __shared__ char Ps[8][2304];
  __shared__ float Ms[4][16], Ls[4][16], Os[4][16][68];
  const int nb = blockIdx.x * 64;
  const int bh = blockIdx.y, b = bh >> 2, h = bh & 3;
  const int srcb = b ^ crossmask;
  const int tid = threadIdx.x, w = tid >> 6, lane = tid & 63;
  const int l4 = lane >> 4, l15 = lane & 15;
  const int qt = w & 3, half = w >> 2;
  char* P = Ps[w];
  const u16* Qb = qbuf + (size_t)b * 262144 + h * 64;
  const u16* Kb = kbuf + (size_t)srcb * 262144 + h * 64;
  const u16* Vb = vbuf + (size_t)srcb * 262144 + (size_t)h * 65536;
  const int srow = tid >> 3, sj = (tid & 7) * 16, sx = sj ^ ((srow & 7) << 4);
  const u16* gK[2] = {Kb, Kb + 512 * 256};
  const u16* gV[2] = {Vb, Vb + 512};

  const int qrow = nb + qt * 16;
  AB qf[2];
#pragma unroll
  for (int ks = 0; ks < 2; ++ks)
    qf[ks].q = *(const u32x4*)(Qb + (size_t)(qrow + l15) * 256 + ks * 32 + l4 * 8);

  u32x4 sk[2], sv[2];
#pragma unroll
  for (int H = 0; H < 2; ++H) {
    sk[H] = *(const u32x4*)((const char*)(gK[H] + (size_t)srow * 256) + sj);
    sv[H] = *(const u32x4*)((const char*)(gV[H] + (size_t)srow * 1024) + sj);
  }
#pragma unroll
  for (int H = 0; H < 2; ++H) {
    *(u32x4*)(Kt[H][0] + srow * 128 + sx) = sk[H];
    *(u32x4*)(Vt[H][0] + srow * 128 + sx) = sv[H];
  }
  __syncthreads();

  f32x4 oacc[4];
#pragma unroll
  for (int s = 0; s < 4; ++s) oacc[s] = (f32x4){0.f, 0.f, 0.f, 0.f};
  float mst = -1e30f, lst = 0.f;

#pragma unroll
  for (int mt = 0; mt < 8; ++mt) {
    const int cur = mt & 1, nx = cur ^ 1;
    if (mt < 7) {
#pragma unroll
      for (int H = 0; H < 2; ++H) {
        sk[H] = *(const u32x4*)((const char*)(gK[H] + (size_t)((mt + 1) * 64 + srow) * 256) + sj);
        sv[H] = *(const u32x4*)((const char*)(gV[H] + (size_t)srow * 1024 + (mt + 1) * 64) + sj);
      }
    }
    f32x4 sa[4];
#pragma unroll
    for (int sm = 0; sm < 4; ++sm) {
      sa[sm] = (f32x4){0.f, 0.f, 0.f, 0.f};
#pragma unroll
      for (int ks = 0; ks < 2; ++ks) {
        AB kf;
        int rr = sm * 16 + l15;
        kf.q = *(const u32x4*)(Kt[half][cur] + rr * 128 + ((ks * 64 + l4 * 16) ^ ((rr & 7) << 4)));
        sa[sm] = __builtin_amdgcn_mfma_f32_16x16x32_bf16(kf.s, qf[ks].s, sa[sm], 0, 0, 0);
      }
    }
    float m1 = fmaxf(fmaxf(fmaxf(sa[0][0], sa[0][1]), fmaxf(sa[0][2], sa[0][3])),
                     fmaxf(fmaxf(sa[1][0], sa[1][1]), fmaxf(sa[1][2], sa[1][3])));
    float m2 = fmaxf(fmaxf(fmaxf(sa[2][0], sa[2][1]), fmaxf(sa[2][2], sa[2][3])),
                     fmaxf(fmaxf(sa[3][0], sa[3][1]), fmaxf(sa[3][2], sa[3][3])));
    m1 = fmaxf(m1, m2);
    m1 = fmaxf(m1, __shfl_xor(m1, 16));
    m1 = fmaxf(m1, __shfl_xor(m1, 32));
    float mnew = fmaxf(mst, m1);
    float corr = __expf(mst - mnew);
    mst = mnew;
    float rs = 0.f;
#pragma unroll
    for (int sm = 0; sm < 4; ++sm)
#pragma unroll
      for (int r = 0; r < 4; ++r) {
        float p = __expf(sa[sm][r] - mnew);
        sa[sm][r] = p;
        rs += p;
      }
    rs += __shfl_xor(rs, 16);
    rs += __shfl_xor(rs, 32);
    lst = lst * corr + rs;
#pragma unroll
    for (int r = 0; r < 4; ++r) {
      float cr = __shfl(corr, l4 * 4 + r);
#pragma unroll
      for (int s = 0; s < 4; ++s) oacc[s][r] *= cr;
    }
#pragma unroll
    for (int sm = 0; sm < 4; ++sm) {
      u32x2 pk;
      pk[0] = (u32)f2bf(sa[sm][0]) | ((u32)f2bf(sa[sm][1]) << 16);
      pk[1] = (u32)f2bf(sa[sm][2]) | ((u32)f2bf(sa[sm][3]) << 16);
      *(u32x2*)(P + l15 * 136 + (sm * 16 + l4 * 4) * 2) = pk;
    }
#pragma unroll
    for (int ks = 0; ks < 2; ++ks) {
      AB pf;
      const char* ra = P + l15 * 136 + ks * 64 + l4 * 16;
      pf.d[0] = *(const u32x2*)ra;
      pf.d[1] = *(const u32x2*)(ra + 8);
#pragma unroll
      for (int s = 0; s < 4; ++s) {
        AB vf;
        int rr = s * 16 + l15;
        vf.q = *(const u32x4*)(Vt[half][cur] + rr * 128 + ((ks * 64 + l4 * 16) ^ ((rr & 7) << 4)));
        oacc[s] = __builtin_amdgcn_mfma_f32_16x16x32_bf16(pf.s, vf.s, oacc[s], 0, 0, 0);
      }
    }
    if (mt < 7) {
#pragma unroll
      for (int H = 0; H < 2; ++H) {
        *(u32x4*)(Kt[H][nx] + srow * 128 + sx) = sk[H];
        *(u32x4*)(Vt[H][nx] + srow * 128 + sx) = sv[H];
      }
    }
    __syncthreads();
  }
  if (half == 1) {
    Ms[qt][l15] = mst;
    Ls[qt][l15] = lst;
#pragma unroll
    for (int s = 0; s < 4; ++s)
#pragma unroll
      for (int r = 0; r < 4; ++r) Os[qt][l4 * 4 + r][s * 16 + l15] = oacc[s][r];
  }
  __syncthreads();
  if (half == 0) {
    float mb = Ms[qt][l15], lb = Ls[qt][l15];
    float M = fmaxf(mst, mb);
    float ea = __expf(mst - M), eb = __expf(mb - M);
    float rl = 1.f / (lst * ea + lb * eb);
    float fa = ea * rl, fb = eb * rl;
#pragma unroll
    for (int r = 0; r < 4; ++r) {
      float far = __shfl(fa, l4 * 4 + r);
      float fbr = __shfl(fb, l4 * 4 + r);
      int n = nb + qt * 16 + l4 * 4 + r;
#pragma unroll
      for (int s = 0; s < 4; ++s) {
        float ov = oacc[s][r] * far + Os[qt][l4 * 4 + r][s * 16 + l15] * fbr;
        att[(size_t)b * 262144 + (size_t)n * 256 + h * 64 + s * 16 + l15] = f2bf(ov);
      }
    }
  }
}

// ---------------- fused post: merge + mlp + residual + next QKV -------------
// grid 256 (16 rows each), 1024 thr / 16 waves; wave owns 16 cols per pass.
__global__ __launch_bounds__(1024) void k_post(
    const u16* __restrict__ att, const u16* __restrict__ wl, const u16* __restrict__ wln,
    const float* __restrict__ bm, const float* __restrict__ sc, const float* __restrict__ sh,
    const float* __restrict__ b2, const float* __restrict__ bqn,
    const float* __restrict__ bkn, const float* __restrict__ bvn,
    float* __restrict__ dstate, u16* __restrict__ y, u16* __restrict__ qb,
    u16* __restrict__ kb, u16* __restrict__ vb, float* __restrict__ out, int cross, int j,
    int last) {
  __shared__ char yT[16384];    // [16 rows][512ch] bf16, 16B-XOR swizzled
  __shared__ char hT[16384];    // att copy, then stage2 output
  __shared__ char Wb[114688];   // 16 per-wave rings x 7KB (D=6, NBUF=7)
  const int bid = blockIdx.x;
  const int row0 = bid * 16, b = row0 >> 10, nb0 = row0 & 1023;
  const int tid = threadIdx.x, w = tid >> 6, lane = tid & 63;
  const int l4 = lane >> 4, l15 = lane & 15;
  char* ring = Wb + w * 7168;

  {  // stage yT (16 rows x 512 ch) + att -> hT (16 rows x 256 ch)
    int rr = tid >> 6, ch = tid & 63;
    u32x4 v = *(const u32x4*)(y + (size_t)(row0 + rr) * 512 + ch * 8);
    *(u32x4*)(yT + ((rr * 1024 + ch * 16) ^ ((rr & 7) << 4))) = v;
    if (tid < 512) {
      int ra = tid >> 5, ca = tid & 31;
      u32x4 va = *(const u32x4*)(att + (size_t)(row0 + ra) * 256 + ca * 8);
      *(u32x4*)(hT + ((ra * 1024 + ca * 16) ^ ((ra & 7) << 4))) = va;
    }
  }
  __syncthreads();
  {  // stage1: msg = att @ Wm^T + bm -> yT[.,256+c]
    f32x4 acc;
    mmw<256, 8, 6>(wl + 196608 + (size_t)(w * 16) * 256, ring, hT, acc, lane, l4, l15,
                   bid & 7);
    int c = w * 16 + l15;
    float bb = bm[c];
#pragma unroll
    for (int r = 0; r < 4; ++r) {
      int rw = l4 * 4 + r;
      *(u16*)(yT + ((rw * 1024 + (256 + c) * 2) ^ ((rw & 7) << 4))) = f2bf(acc[r] + bb);
    }
  }
  __syncthreads();
  {  // stage2: h = relu(sc*(W1 y)+sh) -> hT  (two 256-col passes)
#pragma unroll
    for (int p = 0; p < 2; ++p) {
      f32x4 acc;
      const int colbase = p * 256 + w * 16;
      mmw<512, 16, 6>(wl + 262144 + (size_t)colbase * 512, ring, yT, acc, lane, l4, l15,
                      (bid + p * 5) & 15);
      int c = colbase + l15;
      float s_ = sc[c], t_ = sh[c];
#pragma unroll
      for (int r = 0; r < 4; ++r) {
        int rw = l4 * 4 + r;
        *(u16*)(hT + ((rw * 1024 + c * 2) ^ ((rw & 7) << 4))) =
            f2bf(fmaxf(s_ * acc[r] + t_, 0.f));
      }
    }
  }
  __syncthreads();
  {  // stage3: delta = W2 h + b2 ; residual ; y ; yT x-half ; out
    f32x4 acc;
    mmw<512, 16, 6>(wl + 524288 + (size_t)(w * 16) * 512, ring, hT, acc, lane, l4, l15,
                    bid & 15);
    float* ob = out + (size_t)(((b >> 1) * 9 + j) * 2 + (b & 1)) * 262144;
    int c = w * 16 + l15;
    float bb = b2[c];
#pragma unroll
    for (int r = 0; r < 4; ++r) {
      int rw = l4 * 4 + r;
      size_t di = (size_t)(row0 + rw) * 256 + c;
      float nv = dstate[di] + acc[r] + bb;
      dstate[di] = nv;
      u16 bv16 = f2bf(nv);
      y[(size_t)(row0 + rw) * 512 + c] = bv16;
      *(u16*)(yT + ((rw * 1024 + c * 2) ^ ((rw & 7) << 4))) = bv16;
      if (cross) ob[(size_t)c * 1024 + nb0 + rw] = nv;
    }
  }
  if (last) return;
  __syncthreads();
  {  // stage4: next-layer QKV (three 256-col passes: Q, K, V)
#pragma unroll
    for (int p = 0; p < 3; ++p) {
      f32x4 acc;
      mmw<256, 8, 6>(wln + p * 65536 + (size_t)(w * 16) * 256, ring, yT, acc, lane, l4,
                     l15, (bid + p * 3) & 7);
      int c = w * 16 + l15;
      int borig = ((c & 63) << 2) | (c >> 6);
      if (p == 0) {
        float bb = 0.125f * bqn[borig];
#pragma unroll
        for (int r = 0; r < 4; ++r)
          qb[(size_t)b * 262144 + (size_t)(nb0 + l4 * 4 + r) * 256 + c] = f2bf(acc[r] + bb);
      } else if (p == 1) {
        float bb = bkn[borig];
#pragma unroll
        for (int r = 0; r < 4; ++r)
          kb[(size_t)b * 262144 + (size_t)(nb0 + l4 * 4 + r) * 256 + c] = f2bf(acc[r] + bb);
      } else {
        float bb = bvn[borig];
        u32x2 pk;
        pk[0] = (u32)f2bf(acc[0] + bb) | ((u32)f2bf(acc[1] + bb) << 16);
        pk[1] = (u32)f2bf(acc[2] + bb) | ((u32)f2bf(acc[3] + bb) << 16);
        *(u32x2*)(vb + (size_t)b * 262144 + (size_t)c * 1024 + nb0 + l4 * 4) = pk;
      }
    }
  }
}

// ---------------- host ------------------------------------------------------
extern "C" void kernel_launch(void* const* d_in, const int* in_sizes, int n_in,
                              void* d_out, int out_size, void* d_ws, size_t ws_size,
                              hipStream_t stream) {
  const float* desc0 = (const float*)d_in[0];
  const float* desc1 = (const float*)d_in[1];
  const float* Wq = (const float*)d_in[2];
  const float* bq = (const float*)d_in[3];
  const float* Wk = (const float*)d_in[4];
  const float* bk = (const float*)d_in[5];
  const float* Wv = (const float*)d_in[6];
  const float* bv = (const float*)d_in[7];
  const float* Wm = (const float*)d_in[8];
  const float* bm = (const float*)d_in[9];
  const float* W1 = (const float*)d_in[10];
  const float* b1 = (const float*)d_in[11];
  const float* gamma = (const float*)d_in[12];
  const float* beta = (const float*)d_in[13];
  const float* mu = (const float*)d_in[14];
  const float* var = (const float*)d_in[15];
  const float* W2 = (const float*)d_in[16];
  const float* b2 = (const float*)d_in[17];

  char* ws = (char*)d_ws;
  float* dstate = (float*)ws;                   // 4 MB
  u16* y = (u16*)(ws + ((size_t)4 << 20));      // 4 MB
  u16* qb = (u16*)(ws + ((size_t)8 << 20));     // 2 MB
  u16* kb = (u16*)(ws + ((size_t)10 << 20));    // 2 MB
  u16* vb = (u16*)(ws + ((size_t)12 << 20));    // 2 MB
  u16* attb = (u16*)(ws + ((size_t)14 << 20));  // 2 MB
  u16* wbf = (u16*)(ws + ((size_t)16 << 20));   // 23.6 MB
  float* scb = (float*)(ws + ((size_t)40 << 20));
  float* shb = (float*)(ws + ((size_t)41 << 20));

  k_setup<<<11556, 256, 0, stream>>>(Wq, Wk, Wv, Wm, W1, W2, gamma, beta, mu, var, b1,
                                     wbf, scb, shb);
  k_init<<<dim3(16, 4, 4), 256, 0, stream>>>(desc0, desc1, dstate, y);
  k_qkv0<<<256, 512, 0, stream>>>(y, wbf, bq, bk, bv, qb, kb, vb);

  for (int i = 0; i < 18; ++i) {
    int cross = i & 1;
    const u16* wl = wbf + (size_t)i * 655360;
    int nl = (i < 17) ? i + 1 : 0;
    const u16* wln = wbf + (size_t)nl * 655360;
    k_attn<<<dim3(16, 16), 512, 0, stream>>>(qb, kb, vb, attb, cross ? 2 : 0);
    k_post<<<256, 1024, 0, stream>>>(attb, wl, wln, bm + i * 256, scb + (size_t)i * 512,
                                     shb + (size_t)i * 512, b2 + i * 256, bq + nl * 256,
                                     bk + nl * 256, bv + nl * 256, dstate, y, qb, kb, vb,
                                     (float*)d_out, cross, i >> 1, i == 17);
  }
}